// Round 1
// baseline (675.476 us; speedup 1.0000x reference)
//
#include <hip/hip_runtime.h>
#include <hip/hip_bf16.h>
#include <math.h>

#define B_ 2
#define S_ 2048
#define D_ 256
#define QK_ 256
#define H_ 8
#define HD_ 32
#define MLP_ 1024
#define TOPK_ 8
#define R_ 2048
#define MD_ 64
#define MAXN_ 192

__device__ __constant__ float SCALE_ = 0.17677669529663687f;

// ---------------- adj dtype detection ----------------
__global__ void init_flag(int* flag) { *flag = 0; }

__global__ void detect_adj(const unsigned int* __restrict__ adj, int* __restrict__ flag) {
    long g = (long)blockIdx.x * blockDim.x + threadIdx.x;
    long n = (long)R_ * R_ / 4;   // safe under both interpretations
    int found = 0;
    for (long i = g; i < n; i += (long)gridDim.x * blockDim.x) {
        if (adj[i] > 1u) { found = 1; break; }
    }
    if (found) atomicOr(flag, 1);
}

__device__ inline bool adj_on(const void* adj, int isbyte, long idx) {
    if (isbyte) return ((const unsigned char*)adj)[idx] != 0;
    return ((const int*)adj)[idx] != 0;
}

// ---------------- region memory normalize ----------------
__global__ void norm_rm(const float* __restrict__ rm, float* __restrict__ nm) {
    int r = blockIdx.x, t = threadIdx.x;   // 64 threads
    float v = rm[r * MD_ + t];
    float s = v * v;
    for (int o = 32; o > 0; o >>= 1) s += __shfl_down(s, o);
    s = __shfl(s, 0);
    nm[r * MD_ + t] = v / (sqrtf(s) + 1e-8f);
}

// ---------------- top-8 cosine neighbors per region ----------------
__global__ __launch_bounds__(256) void topk_kernel(const float* __restrict__ nm,
                                                   int* __restrict__ tk) {
    __shared__ float nmr[MD_];
    __shared__ float sv[256];
    __shared__ int   si[256];
    __shared__ int   swin;
    int r = blockIdx.x, t = threadIdx.x;
    if (t < MD_) nmr[t] = nm[r * MD_ + t];
    __syncthreads();
    float simv[8];
#pragma unroll
    for (int k2 = 0; k2 < 8; k2++) {
        int c = t + 256 * k2;
        const float* row = nm + (long)c * MD_;
        float s = 0.f;
#pragma unroll
        for (int d = 0; d < MD_; d++) s = fmaf(nmr[d], row[d], s);
        simv[k2] = (c == r) ? -INFINITY : s;
    }
    for (int it = 0; it < TOPK_; it++) {
        float bv = -INFINITY; int bi = 0x7fffffff;
#pragma unroll
        for (int k2 = 0; k2 < 8; k2++) {
            int c = t + 256 * k2;
            if (simv[k2] > bv || (simv[k2] == bv && c < bi)) { bv = simv[k2]; bi = c; }
        }
        sv[t] = bv; si[t] = bi;
        __syncthreads();
        for (int o = 128; o > 0; o >>= 1) {
            if (t < o) {
                float v2 = sv[t + o]; int i2 = si[t + o];
                if (v2 > sv[t] || (v2 == sv[t] && i2 < si[t])) { sv[t] = v2; si[t] = i2; }
            }
            __syncthreads();
        }
        if (t == 0) { swin = si[0]; tk[r * TOPK_ + it] = si[0]; }
        __syncthreads();
        int w = swin;
        if ((w & 255) == t) simv[w >> 8] = -INFINITY;
        __syncthreads();
    }
}

// ---------------- neighbor list build (adj union topk) ----------------
__global__ __launch_bounds__(256) void build_nbr(const void* __restrict__ adj,
                                                 const int* __restrict__ tk,
                                                 const int* __restrict__ flag,
                                                 int* __restrict__ nbr_idx,
                                                 int* __restrict__ nbr_cnt) {
    __shared__ int cnt;
    int r = blockIdx.x, t = threadIdx.x;
    if (t == 0) cnt = 0;
    __syncthreads();
    int isbyte = *flag;
    for (int c = t; c < S_; c += 256) {
        long idx = (long)r * R_ + c;
        if (adj_on(adj, isbyte, idx)) {
            int p = atomicAdd(&cnt, 1);
            if (p < MAXN_) nbr_idx[r * MAXN_ + p] = c;
        }
    }
    __syncthreads();
    if (t < TOPK_) {
        int c = tk[r * TOPK_ + t];
        long idx = (long)r * R_ + c;
        if (!adj_on(adj, isbyte, idx) && c < S_) {
            int p = atomicAdd(&cnt, 1);
            if (p < MAXN_) nbr_idx[r * MAXN_ + p] = c;
        }
    }
    __syncthreads();
    if (t == 0) nbr_cnt[r] = min(cnt, MAXN_);
}

// ---------------- layernorm (row of 256) ----------------
__global__ __launch_bounds__(256) void ln_kernel(const float* __restrict__ x,
                                                 const float* __restrict__ g,
                                                 const float* __restrict__ b,
                                                 float* __restrict__ y) {
    __shared__ float red[256];
    int row = blockIdx.x, t = threadIdx.x;
    float v = x[(long)row * D_ + t];
    red[t] = v; __syncthreads();
    for (int o = 128; o > 0; o >>= 1) { if (t < o) red[t] += red[t + o]; __syncthreads(); }
    float mean = red[0] / D_;
    __syncthreads();
    float dv = v - mean;
    red[t] = dv * dv; __syncthreads();
    for (int o = 128; o > 0; o >>= 1) { if (t < o) red[t] += red[t + o]; __syncthreads(); }
    float var = red[0] / D_;
    y[(long)row * D_ + t] = dv * rsqrtf(var + 1e-5f) * g[t] + b[t];
}

// ---------------- generic fp32 GEMM: C = A[M,K] @ W[K,N] (+bias)(+accum)(+gelu)(+resid) ----------------
// EPI: 0=none, 1=exact gelu (applied after bias+accum, before resid)
template <int EPI>
__global__ __launch_bounds__(256) void gemm_kernel(const float* __restrict__ A,
                                                   const float* __restrict__ W,
                                                   const float* __restrict__ bias,
                                                   const float* __restrict__ resid,
                                                   float* __restrict__ C,
                                                   int M, int N, int K, int accum) {
    __shared__ float As[16][65];
    __shared__ float Ws[16][64];
    int tid = threadIdx.x;
    int tx = tid & 15, ty = tid >> 4;
    int m0 = blockIdx.y * 64, n0 = blockIdx.x * 64;
    int ac = tid & 15, ar0 = tid >> 4;
    int wc = tid & 63, wr0 = tid >> 6;
    float acc[4][4] = {};
    for (int k0 = 0; k0 < K; k0 += 16) {
#pragma unroll
        for (int qq = 0; qq < 4; qq++) {
            int r = ar0 + 16 * qq;
            As[ac][r] = A[(long)(m0 + r) * K + k0 + ac];
        }
#pragma unroll
        for (int qq = 0; qq < 4; qq++) {
            int kr = wr0 + 4 * qq;
            Ws[kr][wc] = W[(long)(k0 + kr) * N + n0 + wc];
        }
        __syncthreads();
#pragma unroll
        for (int kk = 0; kk < 16; kk++) {
            float a[4], wv[4];
#pragma unroll
            for (int i = 0; i < 4; i++) a[i] = As[kk][ty * 4 + i];
#pragma unroll
            for (int j = 0; j < 4; j++) wv[j] = Ws[kk][tx * 4 + j];
#pragma unroll
            for (int i = 0; i < 4; i++)
#pragma unroll
                for (int j = 0; j < 4; j++)
                    acc[i][j] = fmaf(a[i], wv[j], acc[i][j]);
        }
        __syncthreads();
    }
#pragma unroll
    for (int i = 0; i < 4; i++) {
        int m = m0 + ty * 4 + i;
#pragma unroll
        for (int j = 0; j < 4; j++) {
            int n = n0 + tx * 4 + j;
            float v = acc[i][j];
            if (bias) v += bias[n];
            if (accum) v += C[(long)m * N + n];
            if (EPI == 1) v = 0.5f * v * (1.0f + erff(v * 0.70710678118654752f));
            if (resid) v += resid[(long)m * N + n];
            C[(long)m * N + n] = v;
        }
    }
}

// ---------------- v column sums per (b, h*HD+d) ----------------
__global__ void vsum_kernel(const float* __restrict__ v, float* __restrict__ vs) {
    int g = blockIdx.x * 256 + threadIdx.x;   // 0..511
    int b = g >> 8, c = g & 255;
    float s = 0.f;
    for (int j = 0; j < S_; j++) s += v[((long)b * S_ + j) * QK_ + c];
    vs[b * QK_ + c] = s;
}

// ---------------- sparse attention via neighbor lists ----------------
__global__ __launch_bounds__(256) void attn_kernel(const float* __restrict__ q,
                                                   const float* __restrict__ k,
                                                   const float* __restrict__ v,
                                                   const float* __restrict__ vs,
                                                   const int* __restrict__ ridx,
                                                   const int* __restrict__ nbr_idx,
                                                   const int* __restrict__ nbr_cnt,
                                                   float* __restrict__ out) {
    __shared__ float qs[QK_];
    __shared__ float sj[H_][MAXN_];
    __shared__ int   nb[MAXN_];
    int bi = blockIdx.x;              // b*S + i
    int b = bi / S_, i = bi - b * S_;
    int t = threadIdx.x;
    int h = t >> 5, ln = t & 31;
    int r = ridx[i];
    int cnt = nbr_cnt[r];
    qs[t] = q[(long)bi * QK_ + t];
    for (int p = t; p < cnt; p += 256) nb[p] = nbr_idx[r * MAXN_ + p];
    __syncthreads();
    // pass 1: neighbor scores (lane ln of head h handles neighbors ln, ln+32, ...)
    for (int p = ln; p < cnt; p += 32) {
        int j = nb[p];
        const float* kr = k + ((long)b * S_ + j) * QK_ + h * HD_;
        const float* qh = qs + h * HD_;
        float s = 0.f;
#pragma unroll
        for (int d = 0; d < HD_; d++) s = fmaf(qh[d], kr[d], s);
        sj[h][p] = s * SCALE_;
    }
    __syncthreads();
    // max over ALL scores: zeros are always present (cnt << S), so floor at 0
    float m = 0.0f;
    for (int p = 0; p < cnt; p++) m = fmaxf(m, sj[h][p]);
    float em = expf(-m);
    float Z = (float)(S_ - cnt) * em;
    float accv = 0.f, vn = 0.f;
    int d = ln;
    for (int p = 0; p < cnt; p++) {
        int j = nb[p];
        float vv = v[((long)b * S_ + j) * QK_ + h * HD_ + d];
        float e = expf(sj[h][p] - m);
        Z += e;
        accv = fmaf(e, vv, accv);
        vn += vv;
    }
    float o = (em * (vs[b * QK_ + h * HD_ + d] - vn) + accv) / Z;
    out[(long)bi * QK_ + h * HD_ + d] = o;
}

// ---------------- gate + fuse + LN2 ----------------
__global__ __launch_bounds__(256) void fuse_ln2_kernel(const float* __restrict__ x,
                                                       const float* __restrict__ ao,
                                                       const float* __restrict__ gp,
                                                       const float* __restrict__ g2,
                                                       const float* __restrict__ b2,
                                                       float* __restrict__ fused,
                                                       float* __restrict__ h) {
    __shared__ float red[256];
    int row = blockIdx.x, t = threadIdx.x;
    long idx = (long)row * D_ + t;
    float gate = 1.f / (1.f + expf(-gp[idx]));
    float f = gate * x[idx] + (1.f - gate) * ao[idx];
    fused[idx] = f;
    red[t] = f; __syncthreads();
    for (int o = 128; o > 0; o >>= 1) { if (t < o) red[t] += red[t + o]; __syncthreads(); }
    float mean = red[0] / D_;
    __syncthreads();
    float dv = f - mean;
    red[t] = dv * dv; __syncthreads();
    for (int o = 128; o > 0; o >>= 1) { if (t < o) red[t] += red[t + o]; __syncthreads(); }
    float var = red[0] / D_;
    h[idx] = dv * rsqrtf(var + 1e-5f) * g2[t] + b2[t];
}

extern "C" void kernel_launch(void* const* d_in, const int* in_sizes, int n_in,
                              void* d_out, int out_size, void* d_ws, size_t ws_size,
                              hipStream_t stream) {
    const float* x    = (const float*)d_in[0];
    const int*   ridx = (const int*)d_in[1];
    const void*  adj  = d_in[2];
    const float* rm   = (const float*)d_in[3];
    const float* wq = (const float*)d_in[4],  *bq = (const float*)d_in[5];
    const float* wk = (const float*)d_in[6],  *bk = (const float*)d_in[7];
    const float* wv = (const float*)d_in[8],  *bv = (const float*)d_in[9];
    const float* wo = (const float*)d_in[10], *bo = (const float*)d_in[11];
    const float* ln1g = (const float*)d_in[12], *ln1b = (const float*)d_in[13];
    const float* ln2g = (const float*)d_in[14], *ln2b = (const float*)d_in[15];
    const float* gw  = (const float*)d_in[16], *gb  = (const float*)d_in[17];
    const float* fw1 = (const float*)d_in[18], *fb1 = (const float*)d_in[19];
    const float* fw2 = (const float*)d_in[20], *fb2 = (const float*)d_in[21];
    float* out = (float*)d_out;

    // workspace layout (floats)
    float* wsf     = (float*)d_ws;
    int*   flag    = (int*)d_ws;               // 1 int (padded to 64 floats)
    float* nmb     = wsf + 64;                 // R*MD = 131072
    int*   tk      = (int*)(nmb + 131072);     // R*TOPK = 16384
    int*   nbr_idx = tk + 16384;               // R*MAXN = 393216
    int*   nbr_cnt = nbr_idx + R_ * MAXN_;     // 2048
    float* xn      = (float*)(nbr_cnt + 2048); // 1048576
    float* qb      = xn + 1048576;
    float* kb      = qb + 1048576;
    float* vb      = kb + 1048576;
    float* vs      = vb + 1048576;             // 512
    float* attnO   = vs + 512;                 // 1048576 (pre-wo; reused as gate preact)
    float* attn_out= attnO + 1048576;          // 1048576
    float* fusedb  = attn_out + 1048576;       // 1048576
    float* f1      = fusedb + 1048576;         // B*S*MLP = 4194304

    const int MROWS = B_ * S_;                 // 4096

    init_flag<<<1, 1, 0, stream>>>(flag);
    detect_adj<<<256, 256, 0, stream>>>((const unsigned int*)adj, flag);
    norm_rm<<<R_, 64, 0, stream>>>(rm, nmb);
    topk_kernel<<<R_, 256, 0, stream>>>(nmb, tk);
    build_nbr<<<R_, 256, 0, stream>>>(adj, tk, flag, nbr_idx, nbr_cnt);

    ln_kernel<<<MROWS, 256, 0, stream>>>(x, ln1g, ln1b, xn);

    dim3 gqkv(QK_ / 64, MROWS / 64);
    gemm_kernel<0><<<gqkv, 256, 0, stream>>>(xn, wq, bq, nullptr, qb, MROWS, QK_, D_, 0);
    gemm_kernel<0><<<gqkv, 256, 0, stream>>>(xn, wk, bk, nullptr, kb, MROWS, QK_, D_, 0);
    gemm_kernel<0><<<gqkv, 256, 0, stream>>>(xn, wv, bv, nullptr, vb, MROWS, QK_, D_, 0);

    vsum_kernel<<<2, 256, 0, stream>>>(vb, vs);
    attn_kernel<<<MROWS, 256, 0, stream>>>(qb, kb, vb, vs, ridx, nbr_idx, nbr_cnt, attnO);

    dim3 gd(D_ / 64, MROWS / 64);
    gemm_kernel<0><<<gd, 256, 0, stream>>>(attnO, wo, bo, nullptr, attn_out, MROWS, D_, QK_, 0);

    // gate preact = x @ gw[0:D] + gb  +  attn_out @ gw[D:2D]
    float* gatep = attnO;
    gemm_kernel<0><<<gd, 256, 0, stream>>>(x, gw, gb, nullptr, gatep, MROWS, D_, D_, 0);
    gemm_kernel<0><<<gd, 256, 0, stream>>>(attn_out, gw + (long)D_ * D_, nullptr, nullptr, gatep, MROWS, D_, D_, 1);

    float* hb = xn;  // reuse
    fuse_ln2_kernel<<<MROWS, 256, 0, stream>>>(x, attn_out, gatep, ln2g, ln2b, fusedb, hb);

    dim3 gf1(MLP_ / 64, MROWS / 64);
    gemm_kernel<1><<<gf1, 256, 0, stream>>>(hb, fw1, fb1, nullptr, f1, MROWS, MLP_, D_, 0);
    gemm_kernel<0><<<gd, 256, 0, stream>>>(f1, fw2, fb2, fusedb, out, MROWS, D_, MLP_, 0);
}